// Round 1
// baseline (905.200 us; speedup 1.0000x reference)
//
#include <hip/hip_runtime.h>
#include <hip/hip_bf16.h>

typedef float f32x4 __attribute__((ext_vector_type(4)));
typedef short s16x8 __attribute__((ext_vector_type(8)));

#define MROWS 4096
#define NF 1024      // in-features of big layers
#define OF 1024      // out-features of big layers
#define BM 128
#define BN 128

static __device__ __forceinline__ float silu_f(float x) {
    return x / (1.f + __expf(-x));
}

static __device__ __forceinline__ unsigned short f2bf(float f) {
    unsigned int u = __float_as_uint(f);
    return (unsigned short)((u + 0x7FFFu + ((u >> 16) & 1u)) >> 16);
}

// Cubic B-spline over knots t_j = -2.2 + 0.4*j (j=0..11). Returns 4 tap
// values w[0..3] living at slots p..p+3 of the 8 basis functions; slots
// outside [0,8) (or x outside the knot span) contribute nothing.
static __device__ __forceinline__ void basis_taps(float x, float w[4], int &p) {
    float t  = __fmaf_rn(x, 2.5f, 5.5f);       // (x + 2.2) / 0.4
    float jf = floorf(t);
    float u  = t - jf;
    int   j  = (int)jf;
    float um  = 1.f - u;
    float um2 = um * um;
    float u2  = u * u;
    float w0 = um2 * um * (1.f / 6.f);
    float w3 = u2 * u * (1.f / 6.f);
    float w1 = __fmaf_rn(0.5f * u, u2, -u2) + (2.f / 3.f);  // (3u^3-6u^2+4)/6
    float w2 = 1.f - w0 - w1 - w3;                           // partition of unity
    w[0] = w0; w[1] = w1; w[2] = w2; w[3] = w3;
    p = (j >= 0 && j <= 10) ? (j - 3) : -10000;              // invalid -> no slot hits
}

// LDS helpers: row stride 128B (64 bf16), XOR swizzle byte ^= (row&7)<<4
static __device__ __forceinline__ void st_bf16x4(char* lds, int r, int c4,
                                                 float a, float b, float c, float d) {
    unsigned int lo = (unsigned int)f2bf(a) | ((unsigned int)f2bf(b) << 16);
    unsigned int hi = (unsigned int)f2bf(c) | ((unsigned int)f2bf(d) << 16);
    int byte = r * 128 + (((c4 << 1) ^ ((r & 7) << 4)));
    uint2 v; v.x = lo; v.y = hi;
    *reinterpret_cast<uint2*>(lds + byte) = v;
}

static __device__ __forceinline__ s16x8 ld_frag(const char* lds, int r, int c) {
    int byte = r * 128 + (((c << 1) ^ ((r & 7) << 4)));
    return *reinterpret_cast<const s16x8*>(lds + byte);
}

// Fused KAN-linear as bf16 MFMA GEMM.  Virtual K layout: 16 chunks of 64
// silu-features, then 128 chunks of 8 features x 8 basis slots.
template<int ACT>
__global__ __launch_bounds__(256)
void kan_gemm(const float* __restrict__ X,    // (4096,1024)
              const float* __restrict__ Wb,   // (1024,1024)
              const float* __restrict__ Ws,   // (1024,1024,8)
              const float* __restrict__ Wc,   // (1024,1024)
              float* __restrict__ Out)        // (4096,1024)
{
    __shared__ alignas(16) char As[BM * 128];
    __shared__ alignas(16) char Bs[BN * 128];

    const int t    = threadIdx.x;
    const int lane = t & 63;
    const int wid  = t >> 6;
    const int wr   = wid >> 1;    // wave row (2x2 wave grid, 64x64 per wave)
    const int wcn  = wid & 1;     // wave col
    const int row0 = blockIdx.x * BM;
    const int col0 = blockIdx.y * BN;

    f32x4 acc[4][4];
    #pragma unroll
    for (int i = 0; i < 4; ++i)
        #pragma unroll
        for (int j = 0; j < 4; ++j)
            acc[i][j] = (f32x4){0.f, 0.f, 0.f, 0.f};

    const int rs = t >> 4;           // 0..15
    const int c4 = (t & 15) << 2;    // 0..60 step 4

    for (int ch = 0; ch < 144; ++ch) {
        __syncthreads();
        if (ch < 16) {
            // ---- base phase: A = silu(x), B = base_w (both fp32->bf16) ----
            const int i0 = ch << 6;
            #pragma unroll
            for (int ps = 0; ps < 8; ++ps) {
                const int rr = (ps << 4) + rs;
                float4 xv = *(const float4*)(X + (size_t)(row0 + rr) * NF + i0 + c4);
                st_bf16x4(As, rr, c4, silu_f(xv.x), silu_f(xv.y), silu_f(xv.z), silu_f(xv.w));
                float4 wv = *(const float4*)(Wb + (size_t)(col0 + rr) * NF + i0 + c4);
                st_bf16x4(Bs, rr, c4, wv.x, wv.y, wv.z, wv.w);
            }
        } else {
            // ---- spline phase: 8 features, 8 basis slots each ----
            const int f0 = (ch - 16) << 3;
            #pragma unroll
            for (int ps = 0; ps < 8; ++ps) {
                const int rr = (ps << 4) + rs;
                float4 sv = *(const float4*)(Ws + (size_t)(col0 + rr) * (NF * 8) + (f0 << 3) + c4);
                float  sc = Wc[(size_t)(col0 + rr) * NF + f0 + (c4 >> 3)];
                st_bf16x4(Bs, rr, c4, sv.x * sc, sv.y * sc, sv.z * sc, sv.w * sc);
            }
            {
                const int rr = t >> 1;
                const int fh = (t & 1) << 2;   // this thread's 4 features
                float4 xv = *(const float4*)(X + (size_t)(row0 + rr) * NF + f0 + fh);
                float xs[4] = {xv.x, xv.y, xv.z, xv.w};
                #pragma unroll
                for (int ff = 0; ff < 4; ++ff) {
                    float w[4]; int p;
                    basis_taps(xs[ff], w, p);
                    unsigned long long taps =
                          (unsigned long long)f2bf(w[0])
                        | ((unsigned long long)f2bf(w[1]) << 16)
                        | ((unsigned long long)f2bf(w[2]) << 32)
                        | ((unsigned long long)f2bf(w[3]) << 48);
                    int bsh = p << 4;          // bit position of slot p
                    unsigned long long lo = 0ull, hi = 0ull;
                    if (bsh >= 0) {
                        if (bsh < 64)       { lo = taps << bsh; hi = bsh ? (taps >> (64 - bsh)) : 0ull; }
                        else if (bsh < 128) { hi = taps << (bsh - 64); }
                    } else if (bsh > -64)   { lo = taps >> (-bsh); }
                    const int cc   = (fh + ff) << 3;   // slot-0 element index
                    const int byte = rr * 128 + (((cc << 1) ^ ((rr & 7) << 4)));
                    uint4 v;
                    v.x = (unsigned int)lo; v.y = (unsigned int)(lo >> 32);
                    v.z = (unsigned int)hi; v.w = (unsigned int)(hi >> 32);
                    *reinterpret_cast<uint4*>(As + byte) = v;
                }
            }
        }
        __syncthreads();

        #pragma unroll
        for (int ks = 0; ks < 2; ++ks) {
            const int kc = (ks << 5) + ((lane >> 4) << 3);
            s16x8 af[4], bfr[4];
            #pragma unroll
            for (int i = 0; i < 4; ++i) {
                af[i]  = ld_frag(As, (wr  << 6) + (i << 4) + (lane & 15), kc);
                bfr[i] = ld_frag(Bs, (wcn << 6) + (i << 4) + (lane & 15), kc);
            }
            #pragma unroll
            for (int i = 0; i < 4; ++i)
                #pragma unroll
                for (int j = 0; j < 4; ++j)
                    acc[i][j] = __builtin_amdgcn_mfma_f32_16x16x32_bf16(af[i], bfr[j], acc[i][j], 0, 0, 0);
        }
    }

    // epilogue: C/D map col=lane&15, row=(lane>>4)*4+q  [m89/m91 verified]
    const int crow = (lane >> 4) << 2;
    const int ccol = lane & 15;
    #pragma unroll
    for (int i = 0; i < 4; ++i)
        #pragma unroll
        for (int j = 0; j < 4; ++j)
            #pragma unroll
            for (int q = 0; q < 4; ++q) {
                int r = row0 + (wr  << 6) + (i << 4) + crow + q;
                int c = col0 + (wcn << 6) + (j << 4) + ccol;
                float v = acc[i][j][q];
                if (ACT) v = (v >= 0.f) ? v : 0.1f * v;
                Out[(size_t)r * OF + c] = v;
            }
}

// Fused layers 2+3: per (b,d) reduce over H=64 (KAN H->1), then expand 1->H,
// transpose + leaky into x_de.  One thread per (b,d).
__global__ __launch_bounds__(256)
void kan_mid(const float* __restrict__ xemb,   // (64,64,1024) post-leaky
             const float* __restrict__ w2b, const float* __restrict__ w2s, const float* __restrict__ w2c,
             const float* __restrict__ w3b, const float* __restrict__ w3s, const float* __restrict__ w3c,
             float* __restrict__ xcomb,        // (64,1024)
             float* __restrict__ xde)          // (64,64,1024) post-leaky
{
    __shared__ float s_w2sc[64][8];
    __shared__ float s_w2b[64];
    __shared__ float s_w3sc[64][8];
    __shared__ float s_w3b[64];
    const int t = threadIdx.x;
    if (t < 64) { s_w2b[t] = w2b[t]; s_w3b[t] = w3b[t]; }
    for (int i = t; i < 512; i += 256) {
        s_w2sc[i >> 3][i & 7] = w2s[i] * w2c[i >> 3];
        s_w3sc[i >> 3][i & 7] = w3s[i] * w3c[i >> 3];
    }
    __syncthreads();

    const int gid = blockIdx.x * 256 + t;
    const int b = gid >> 10, d = gid & 1023;

    float accv = 0.f;
    for (int h = 0; h < 64; ++h) {
        float e = xemb[((size_t)(b * 64 + h) << 10) + d];
        float w[4]; int p;
        basis_taps(e, w, p);
        float sp = 0.f;
        #pragma unroll
        for (int m = 0; m < 4; ++m) {
            int idx = p + m;
            if ((unsigned)idx < 8u) sp += w[m] * s_w2sc[h][idx];
        }
        accv += silu_f(e) * s_w2b[h] + sp;
    }
    xcomb[gid] = accv;

    float w[4]; int p;
    basis_taps(accv, w, p);
    float sl = silu_f(accv);
    for (int h = 0; h < 64; ++h) {
        float sp = 0.f;
        #pragma unroll
        for (int m = 0; m < 4; ++m) {
            int idx = p + m;
            if ((unsigned)idx < 8u) sp += w[m] * s_w3sc[h][idx];
        }
        float v = sl * s_w3b[h] + sp;
        v = (v >= 0.f) ? v : 0.1f * v;
        xde[((size_t)(b * 64 + h) << 10) + d] = v;
    }
}

extern "C" void kernel_launch(void* const* d_in, const int* in_sizes, int n_in,
                              void* d_out, int out_size, void* d_ws, size_t ws_size,
                              hipStream_t stream)
{
    const float* x   = (const float*)d_in[0];
    const float* w1b = (const float*)d_in[1];
    const float* w1s = (const float*)d_in[2];
    const float* w1c = (const float*)d_in[3];
    const float* w2b = (const float*)d_in[4];
    const float* w2s = (const float*)d_in[5];
    const float* w2c = (const float*)d_in[6];
    const float* w3b = (const float*)d_in[7];
    const float* w3s = (const float*)d_in[8];
    const float* w3c = (const float*)d_in[9];
    const float* w4b = (const float*)d_in[10];
    const float* w4s = (const float*)d_in[11];
    const float* w4c = (const float*)d_in[12];

    float* out    = (float*)d_out;
    float* x_dec  = out;               // (64,64,1024)
    float* x_emb  = out + 4194304;     // (64,64,1024)
    float* x_de   = out + 8388608;     // (64,64,1024)
    float* x_comb = out + 12582912;    // (64,1,1024) == (64,1024)

    dim3 gg(32, 8);
    kan_gemm<1><<<gg, 256, 0, stream>>>(x, w1b, w1s, w1c, x_emb);
    kan_mid<<<256, 256, 0, stream>>>(x_emb, w2b, w2s, w2c, w3b, w3s, w3c, x_comb, x_de);
    kan_gemm<0><<<gg, 256, 0, stream>>>(x_de, w4b, w4s, w4c, x_dec);
}